// Round 1
// baseline (459.052 us; speedup 1.0000x reference)
//
#include <hip/hip_runtime.h>
#include <hip/hip_bf16.h>

// Problem constants
#define B_ 16
#define C_ 64
#define H_ 192
#define W_ 192

// Main-kernel tile config
#define TR 4     // output rows per block
#define TC 48    // output cols per block
#define PCH 72   // padded channel stride (64 + 8) -> 144B: 16B-aligned b128 frags, balanced banks

typedef short bf16x8 __attribute__((ext_vector_type(8)));   // 8 bf16 = 4 VGPRs (guide §3)
typedef float f32x4  __attribute__((ext_vector_type(4)));   // MFMA accumulator

static __device__ __forceinline__ unsigned short f2bf(float f) {
    union { float f; unsigned u; } v; v.f = f;
    unsigned r = v.u + 0x7fff + ((v.u >> 16) & 1);   // RNE
    return (unsigned short)(r >> 16);
}
static __device__ __forceinline__ float bf2f(unsigned short u) {
    union { unsigned u; float f; } v; v.u = ((unsigned)u) << 16; return v.f;
}

// ---------------- Kernel 1: dynamic depthwise kernels (fp32, exact) ----------------
// hid = leaky(k_v @ W1^T, 0.1); kern[b][c*9+j] = hid @ W2^T
__global__ void kgen(const float* __restrict__ k_v, const float* __restrict__ W1,
                     const float* __restrict__ W2, float* __restrict__ kern) {
    int b = blockIdx.x, c = threadIdx.x;     // 16 blocks x 64 threads
    __shared__ float kv[64], hid[64];
    kv[c] = k_v[b * 64 + c];
    __syncthreads();
    float s = 0.f;
#pragma unroll
    for (int k = 0; k < 64; ++k) s += kv[k] * W1[c * 64 + k];
    hid[c] = s > 0.f ? s : 0.1f * s;
    __syncthreads();
    for (int j = 0; j < 9; ++j) {
        int o = c * 9 + j;
        float t = 0.f;
#pragma unroll
        for (int k = 0; k < 64; ++k) t += hid[k] * W2[o * 64 + k];
        kern[b * 576 + o] = t;
    }
}

// ---------------- Kernel 2: conv_w (c_out,c_in,3,3) -> wT[tap][c_out][c_in] bf16 ----
__global__ void wtrans(const float* __restrict__ conv_w, unsigned short* __restrict__ wT) {
    int idx = blockIdx.x * 256 + threadIdx.x;   // 144*256 = 36864 exact
    int tap = idx >> 12;
    int rem = idx & 4095;
    int n = rem >> 6;        // c_out
    int k = rem & 63;        // c_in
    wT[idx] = f2bf(conv_w[(n * 64 + k) * 9 + tap]);
}

// ---------------- Kernel 3: fused static conv (MFMA) + depthwise + epilogue --------
__global__ __launch_bounds__(256, 3)
void fused_conv(const float* __restrict__ x, const unsigned short* __restrict__ wT,
                const float* __restrict__ kern, const float* __restrict__ conv_b,
                float* __restrict__ out) {
    const int bx = blockIdx.x;   // 0..3   col tile
    const int by = blockIdx.y;   // 0..47  row tile
    const int b  = blockIdx.z;   // 0..15  batch
    const int tid  = threadIdx.x;
    const int lane = tid & 63;
    const int wv   = tid >> 6;   // wave id = output row within tile (0..3)
    const int n0   = lane & 15;
    const int q    = lane >> 4;

    const int r0 = by * TR;
    const int c0 = bx * TC;

    // xs: [6 rows][50 cols][PCH ch] bf16 = 43200 B ; bs: [64 n][PCH k] bf16 = 9216 B
    __shared__ __align__(16) unsigned short smem[6 * 50 * PCH + 64 * PCH];
    unsigned short* xs = smem;
    unsigned short* bs = smem + 6 * 50 * PCH;

    // ---- stage x tile: all 64 channels, rows r0-1..r0+4, cols c0-1..c0+48 ----
    for (int i = tid; i < 6 * 50 * 64; i += 256) {      // 75 iters/thread, exact
        int ch = i / 300;
        int rc = i % 300;
        int r = rc / 50, c = rc % 50;
        int gr = r0 + r - 1, gc = c0 + c - 1;
        float v = 0.f;
        if (gr >= 0 && gr < H_ && gc >= 0 && gc < W_)
            v = x[((b * C_ + ch) * H_ + gr) * W_ + gc];
        xs[(r * 50 + c) * PCH + ch] = f2bf(v);
    }

    f32x4 acc[3][4];
#pragma unroll
    for (int i = 0; i < 3; ++i)
#pragma unroll
        for (int j = 0; j < 4; ++j) acc[i][j] = (f32x4){0.f, 0.f, 0.f, 0.f};

    // ---- K loop: 9 taps x 2 k-chunks of 32 channels ----
    for (int tap = 0; tap < 9; ++tap) {
        __syncthreads();   // xs ready (tap 0) / previous tap's bs reads done
        {   // stage B for this tap: 64 c_out x 64 c_in bf16, 16 ch per thread
            int n  = tid >> 2;
            int kb = (tid & 3) * 16;
            const unsigned short* src = wT + tap * 4096 + n * 64 + kb;
            *(bf16x8*)(bs + n * PCH + kb)     = *(const bf16x8*)(src);
            *(bf16x8*)(bs + n * PCH + kb + 8) = *(const bf16x8*)(src + 8);
        }
        __syncthreads();
        const int dr = tap / 3, dc = tap % 3;

        bf16x8 bf[4][2];
#pragma unroll
        for (int nt = 0; nt < 4; ++nt)
#pragma unroll
            for (int ks = 0; ks < 2; ++ks)
                bf[nt][ks] = *(const bf16x8*)(bs + (nt * 16 + n0) * PCH + ks * 32 + q * 8);

#pragma unroll
        for (int cb = 0; cb < 3; ++cb) {
            // A operand: m = lane&15 -> pixel col within 16-block; k = q*8+j (+32*ks)
            const int col = cb * 16 + n0 + dc;      // xs col (0..49)
            const int row = wv + dr;                // xs row (0..5)
            const unsigned short* ap = xs + (row * 50 + col) * PCH + q * 8;
            bf16x8 a0 = *(const bf16x8*)(ap);
            bf16x8 a1 = *(const bf16x8*)(ap + 32);
#pragma unroll
            for (int nt = 0; nt < 4; ++nt) {
                acc[cb][nt] = __builtin_amdgcn_mfma_f32_16x16x32_bf16(a0, bf[nt][0], acc[cb][nt], 0, 0, 0);
                acc[cb][nt] = __builtin_amdgcn_mfma_f32_16x16x32_bf16(a1, bf[nt][1], acc[cb][nt], 0, 0, 0);
            }
        }
    }

    // ---- epilogue: reuse bs region for kern (576 f32) + conv_b (64 f32) ----
    __syncthreads();   // all bs reads drained before overwrite
    float* kf = (float*)(smem + 6 * 50 * PCH);
    for (int i = tid; i < 640; i += 256)
        kf[i] = (i < 576) ? kern[b * 576 + i] : conv_b[i - 576];
    __syncthreads();

#pragma unroll
    for (int nt = 0; nt < 4; ++nt) {
        const int n = nt * 16 + n0;          // c_out  (C/D: col = lane&15)
        float kw[9];
#pragma unroll
        for (int j = 0; j < 9; ++j) kw[j] = kf[n * 9 + j];
        const float bias = kf[576 + n];
#pragma unroll
        for (int cb = 0; cb < 3; ++cb) {
            const int colb = cb * 16 + q * 4;        // C/D: row = q*4 + r -> pixel col
            // depthwise window for this lane's 4 pixels: 3 rows x 6 cols, channel n
            float xw[3][6];
#pragma unroll
            for (int d = 0; d < 3; ++d)
#pragma unroll
                for (int cc = 0; cc < 6; ++cc)
                    xw[d][cc] = bf2f(xs[((wv + d) * 50 + colb + cc) * PCH + n]);
            float4 st;
#pragma unroll
            for (int r = 0; r < 4; ++r) {
                float dw = 0.f;
#pragma unroll
                for (int d = 0; d < 3; ++d)
#pragma unroll
                    for (int e = 0; e < 3; ++e)
                        dw += kw[d * 3 + e] * xw[d][r + e];
                float v = (dw > 0.f ? dw : 0.1f * dw) + acc[cb][nt][r] + bias;
                ((float*)&st)[r] = v;
            }
            float* op = out + ((b * C_ + n) * H_ + (r0 + wv)) * W_ + c0 + colb;
            *(float4*)op = st;   // 16B aligned, 64B/c_out across the quad
        }
    }
}

extern "C" void kernel_launch(void* const* d_in, const int* in_sizes, int n_in,
                              void* d_out, int out_size, void* d_ws, size_t ws_size,
                              hipStream_t stream) {
    const float* x      = (const float*)d_in[0];
    const float* k_v    = (const float*)d_in[1];
    const float* W1     = (const float*)d_in[2];
    const float* W2     = (const float*)d_in[3];
    const float* conv_w = (const float*)d_in[4];
    const float* conv_b = (const float*)d_in[5];
    float* outp = (float*)d_out;

    float* kern        = (float*)d_ws;                               // 36864 B
    unsigned short* wT = (unsigned short*)((char*)d_ws + 40960);     // 73728 B

    kgen<<<16, 64, 0, stream>>>(k_v, W1, W2, kern);
    wtrans<<<144, 256, 0, stream>>>(conv_w, wT);
    dim3 grid(4, 48, 16);
    fused_conv<<<grid, 256, 0, stream>>>(x, wT, kern, conv_b, outp);
}

// Round 2
// 418.019 us; speedup vs baseline: 1.0982x; 1.0982x over previous
//
#include <hip/hip_runtime.h>

#define B_ 16
#define C_ 64
#define H_ 192
#define W_ 192
#define TR 4
#define TC 48

typedef short bf16x8 __attribute__((ext_vector_type(8)));
typedef float f32x4  __attribute__((ext_vector_type(4)));

static __device__ __forceinline__ unsigned short f2bf(float f) {
    union { float f; unsigned u; } v; v.f = f;
    unsigned r = v.u + 0x7fff + ((v.u >> 16) & 1);   // RNE
    return (unsigned short)(r >> 16);
}
static __device__ __forceinline__ float bf2f(unsigned short u) {
    union { unsigned u; float f; } v; v.u = ((unsigned)u) << 16; return v.f;
}
// swizzled xs index (in shorts): pixel p (0..299), channel ch (0..63)
// layout: 300 rows x 128B; granule (8ch=16B) column rotated by p&7 -> conflict-free b128
static __device__ __forceinline__ int xsw(int p, int ch) {
    return p * 64 + (((ch >> 3) ^ (p & 7)) << 3) + (ch & 7);
}

// ---------------- kgen1: hid = leaky(k_v @ W1^T) ----------------
__global__ void kgen1(const float* __restrict__ k_v, const float* __restrict__ W1,
                      float* __restrict__ hid) {
    int b = blockIdx.x, c = threadIdx.x;    // 16 x 64
    __shared__ float kv[64];
    kv[c] = k_v[b * 64 + c];
    __syncthreads();
    float s = 0.f;
#pragma unroll
    for (int k = 0; k < 64; ++k) s += kv[k] * W1[c * 64 + k];
    hid[b * 64 + c] = s > 0.f ? s : 0.1f * s;
}

// ---------------- kgen2: kern = hid @ W2^T (9216 outputs) ----------------
__global__ void kgen2(const float* __restrict__ hid, const float* __restrict__ W2,
                      float* __restrict__ kern) {
    int idx = blockIdx.x * 256 + threadIdx.x;   // 36*256 = 9216 exact
    int b = idx / 576, o = idx - b * 576;
    const float* h = hid + b * 64;
    const float* w = W2 + o * 64;
    float t = 0.f;
#pragma unroll
    for (int k = 0; k < 64; ++k) t += h[k] * w[k];
    kern[idx] = t;
}

// ---------------- wtrans: conv_w (n,k,3,3) -> wT[tap][n][k] bf16 ----------------
__global__ void wtrans(const float* __restrict__ conv_w, unsigned short* __restrict__ wT) {
    int idx = blockIdx.x * 256 + threadIdx.x;   // 144*256 = 36864 exact
    int tap = idx >> 12;
    int rem = idx & 4095;
    int n = rem >> 6, k = rem & 63;
    wT[idx] = f2bf(conv_w[(n * 64 + k) * 9 + tap]);
}

// ---------------- fused: MFMA static conv + depthwise + epilogue, ONE barrier ------
__global__ __launch_bounds__(256, 3)
void fused_conv(const float* __restrict__ x, const unsigned short* __restrict__ wT,
                const float* __restrict__ kern, const float* __restrict__ conv_b,
                float* __restrict__ out) {
    const int bx = blockIdx.x;   // 0..3
    const int by = blockIdx.y;   // 0..47
    const int b  = blockIdx.z;   // 0..15
    const int tid  = threadIdx.x;
    const int lane = tid & 63;
    const int wv   = tid >> 6;
    const int n0   = lane & 15;
    const int q    = lane >> 4;
    const int r0 = by * TR;
    const int c0 = bx * TC;

    // xs: 300 pixels (6 rows x 50 cols) x 64 ch bf16, granule-swizzled = 38400 B
    __shared__ __align__(16) unsigned short xs[6 * 50 * 64];

    // ---- stage interior cols (sc 1..48 -> gc c0..c0+47, always in-bounds in W) ----
    // 576 units = chg(8) x row(6) x cgroup(12); each: 8 x float4 load, 4 x b128 write
    for (int u = tid; u < 576; u += 256) {
        int chg  = u / 72;
        int rest = u - chg * 72;
        int row  = rest / 12;
        int cg   = rest - row * 12;
        int gr   = r0 + row - 1;
        bool in  = (gr >= 0 && gr < H_);
        int grc  = in ? gr : 0;
        const float* xp = x + ((size_t)(b * 64 + chg * 8) * H_ + grc) * W_ + c0 + cg * 4;
        float4 f[8];
#pragma unroll
        for (int j = 0; j < 8; ++j)
            f[j] = in ? *(const float4*)(xp + j * H_ * W_) : make_float4(0.f, 0.f, 0.f, 0.f);
#pragma unroll
        for (int e = 0; e < 4; ++e) {
            int p = row * 50 + 1 + cg * 4 + e;
            union { bf16x8 v; unsigned short s[8]; } wv8;
#pragma unroll
            for (int j = 0; j < 8; ++j) wv8.s[j] = f2bf(((const float*)&f[j])[e]);
            *(bf16x8*)(xs + xsw(p, chg * 8)) = wv8.v;
        }
    }
    // ---- stage edge cols sc=0 (gc=c0-1) and sc=49 (gc=c0+48): 96 units ----
    if (tid < 96) {
        int chg  = tid / 12;
        int rest = tid - chg * 12;
        int row  = rest >> 1;
        int sc   = (rest & 1) ? 49 : 0;
        int gr = r0 + row - 1, gc = c0 + sc - 1;
        bool in = (gr >= 0 && gr < H_ && gc >= 0 && gc < W_);
        union { bf16x8 v; unsigned short s[8]; } wv8;
#pragma unroll
        for (int j = 0; j < 8; ++j) {
            float vv = 0.f;
            if (in) vv = x[((size_t)(b * 64 + chg * 8 + j) * H_ + gr) * W_ + gc];
            wv8.s[j] = f2bf(vv);
        }
        *(bf16x8*)(xs + xsw(row * 50 + sc, chg * 8)) = wv8.v;
    }

    f32x4 acc[3][4];
#pragma unroll
    for (int i = 0; i < 3; ++i)
#pragma unroll
        for (int j = 0; j < 4; ++j) acc[i][j] = (f32x4){0.f, 0.f, 0.f, 0.f};

    __syncthreads();   // the ONE barrier

    // ---- K loop: 9 taps, B fragments straight from global (L2-resident 73.7 KB) ----
#pragma unroll
    for (int tap = 0; tap < 9; ++tap) {
        const int dr = tap / 3, dc = tap % 3;
        bf16x8 bf[4][2];
#pragma unroll
        for (int nt = 0; nt < 4; ++nt)
#pragma unroll
            for (int ks = 0; ks < 2; ++ks)
                bf[nt][ks] = *(const bf16x8*)(wT + tap * 4096 + (nt * 16 + n0) * 64 + ks * 32 + q * 8);
#pragma unroll
        for (int cb = 0; cb < 3; ++cb) {
            const int p = (wv + dr) * 50 + cb * 16 + n0 + dc;
            bf16x8 a0 = *(const bf16x8*)(xs + p * 64 + ((q ^ (p & 7)) << 3));
            bf16x8 a1 = *(const bf16x8*)(xs + p * 64 + (((q + 4) ^ (p & 7)) << 3));
#pragma unroll
            for (int nt = 0; nt < 4; ++nt) {
                acc[cb][nt] = __builtin_amdgcn_mfma_f32_16x16x32_bf16(a0, bf[nt][0], acc[cb][nt], 0, 0, 0);
                acc[cb][nt] = __builtin_amdgcn_mfma_f32_16x16x32_bf16(a1, bf[nt][1], acc[cb][nt], 0, 0, 0);
            }
        }
    }

    // ---- epilogue: depthwise from xs + kern/bias from global (L2-hot) ----
    const float* kp = kern + b * 576;
#pragma unroll
    for (int nt = 0; nt < 4; ++nt) {
        const int n = nt * 16 + n0;
        float kw[9];
#pragma unroll
        for (int j = 0; j < 9; ++j) kw[j] = kp[n * 9 + j];
        const float bias = conv_b[n];
        const int gn = n >> 3, n7 = n & 7;
#pragma unroll
        for (int cb = 0; cb < 3; ++cb) {
            const int colb = cb * 16 + q * 4;
            float xw[3][6];
#pragma unroll
            for (int d = 0; d < 3; ++d)
#pragma unroll
                for (int cc = 0; cc < 6; ++cc) {
                    int p = (wv + d) * 50 + colb + cc;
                    xw[d][cc] = bf2f(xs[p * 64 + ((gn ^ (p & 7)) << 3) + n7]);
                }
            float4 st;
#pragma unroll
            for (int r = 0; r < 4; ++r) {
                float dw = 0.f;
#pragma unroll
                for (int d = 0; d < 3; ++d)
#pragma unroll
                    for (int e = 0; e < 3; ++e)
                        dw += kw[d * 3 + e] * xw[d][r + e];
                float v = (dw > 0.f ? dw : 0.1f * dw) + acc[cb][nt][r] + bias;
                ((float*)&st)[r] = v;
            }
            *(float4*)(out + ((size_t)(b * 64 + n) * H_ + (r0 + wv)) * W_ + c0 + colb) = st;
        }
    }
}

extern "C" void kernel_launch(void* const* d_in, const int* in_sizes, int n_in,
                              void* d_out, int out_size, void* d_ws, size_t ws_size,
                              hipStream_t stream) {
    const float* x      = (const float*)d_in[0];
    const float* k_v    = (const float*)d_in[1];
    const float* W1     = (const float*)d_in[2];
    const float* W2     = (const float*)d_in[3];
    const float* conv_w = (const float*)d_in[4];
    const float* conv_b = (const float*)d_in[5];
    float* outp = (float*)d_out;

    float* kern        = (float*)d_ws;                               // 36864 B
    unsigned short* wT = (unsigned short*)((char*)d_ws + 40960);     // 73728 B
    float* hid         = (float*)((char*)d_ws + 114688);             // 4096 B

    kgen1<<<16, 64, 0, stream>>>(k_v, W1, hid);
    kgen2<<<36, 256, 0, stream>>>(hid, W2, kern);
    wtrans<<<144, 256, 0, stream>>>(conv_w, wT);
    dim3 grid(4, 48, 16);
    fused_conv<<<grid, 256, 0, stream>>>(x, wT, kern, conv_b, outp);
}

// Round 3
// 406.051 us; speedup vs baseline: 1.1305x; 1.0295x over previous
//
#include <hip/hip_runtime.h>

#define B_ 16
#define C_ 64
#define H_ 192
#define W_ 192
#define TR 4
#define TC 48

typedef short bf16x8 __attribute__((ext_vector_type(8)));
typedef float f32x4  __attribute__((ext_vector_type(4)));

static __device__ __forceinline__ unsigned short f2bf(float f) {
    union { float f; unsigned u; } v; v.f = f;
    unsigned r = v.u + 0x7fff + ((v.u >> 16) & 1);   // RNE
    return (unsigned short)(r >> 16);
}
static __device__ __forceinline__ float bf2f(unsigned short u) {
    union { unsigned u; float f; } v; v.u = ((unsigned)u) << 16; return v.f;
}
// swizzled xs index (shorts): pixel p (0..299), channel ch (0..63)
// 300 rows x 128B; 16B granule column rotated by p&7 -> conflict-free b128
static __device__ __forceinline__ int xsw(int p, int ch) {
    return p * 64 + (((ch >> 3) ^ (p & 7)) << 3) + (ch & 7);
}

// ---- prep: kernel-MLP (blocks 0..15) + conv_w transpose->bf16 (blocks 16..159) ----
__global__ void prep(const float* __restrict__ k_v, const float* __restrict__ W1,
                     const float* __restrict__ W2, const float* __restrict__ conv_w,
                     float* __restrict__ kern, unsigned short* __restrict__ wT) {
    const int blk = blockIdx.x, tid = threadIdx.x;
    if (blk < 16) {
        __shared__ float kv[64], hid[64];
        const int b = blk;
        if (tid < 64) kv[tid] = k_v[b * 64 + tid];
        __syncthreads();
        if (tid < 64) {
            float s = 0.f;
#pragma unroll
            for (int k = 0; k < 64; ++k) s += kv[k] * W1[tid * 64 + k];
            hid[tid] = s > 0.f ? s : 0.1f * s;
        }
        __syncthreads();
        for (int o = tid; o < 576; o += 256) {
            const float* w = W2 + o * 64;
            float t = 0.f;
#pragma unroll
            for (int k = 0; k < 64; ++k) t += hid[k] * w[k];
            kern[b * 576 + o] = t;
        }
    } else {
        int idx = (blk - 16) * 256 + tid;     // 144*256 = 36864 exact
        int tap = idx >> 12;
        int rem = idx & 4095;
        int n = rem >> 6, k = rem & 63;
        wT[idx] = f2bf(conv_w[(n * 64 + k) * 9 + tap]);
    }
}

// ---- fused: MFMA static conv + depthwise + epilogue; one barrier; XCD swizzle ----
__global__ __launch_bounds__(256, 3)
void fused_conv(const float* __restrict__ x, const unsigned short* __restrict__ wT,
                const float* __restrict__ kern, const float* __restrict__ conv_b,
                float* __restrict__ out) {
    // --- XCD-locality remap: assume xcd = linear_id % 8 (round-robin dispatch).
    // XCD g owns batches {2g, 2g+1}; within an XCD, work runs bx-fastest then
    // by 0..47 -> row-halos and 48-col write boundaries complete in-XCD-L2.
    const int L = blockIdx.x + 4 * (blockIdx.y + 48 * blockIdx.z);
    const int g = L & 7;
    const int s = L >> 3;                 // 0..383
    const int bx = s & 3;
    const int sl = s >> 2;                // 0..95
    const int by = sl % 48;
    const int b  = (g << 1) + (sl / 48);  // 0..15

    const int tid  = threadIdx.x;
    const int lane = tid & 63;
    const int wv   = tid >> 6;
    const int n0   = lane & 15;
    const int q    = lane >> 4;
    const int r0 = by * TR;
    const int c0 = bx * TC;

    __shared__ __align__(16) unsigned short xs[6 * 50 * 64];   // 38400 B

    // B fragments for tap 0 load before the barrier (overlap with staging)
    const unsigned short* wbase = wT + n0 * 64 + q * 8;
    bf16x8 bcur[4][2], bnxt[4][2];
#pragma unroll
    for (int nt = 0; nt < 4; ++nt)
#pragma unroll
        for (int ks = 0; ks < 2; ++ks)
            bcur[nt][ks] = *(const bf16x8*)(wbase + nt * 1024 + ks * 32);

    // ---- stage interior cols (sc 1..48) ----
    for (int u = tid; u < 576; u += 256) {
        int chg  = u / 72;
        int rest = u - chg * 72;
        int row  = rest / 12;
        int cg   = rest - row * 12;
        int gr   = r0 + row - 1;
        bool in  = (gr >= 0 && gr < H_);
        int grc  = in ? gr : 0;
        const float* xp = x + ((size_t)(b * 64 + chg * 8) * H_ + grc) * W_ + c0 + cg * 4;
        float4 f[8];
#pragma unroll
        for (int j = 0; j < 8; ++j)
            f[j] = in ? *(const float4*)(xp + j * H_ * W_) : make_float4(0.f, 0.f, 0.f, 0.f);
#pragma unroll
        for (int e = 0; e < 4; ++e) {
            int p = row * 50 + 1 + cg * 4 + e;
            union { bf16x8 v; unsigned short s8[8]; } pk;
#pragma unroll
            for (int j = 0; j < 8; ++j) pk.s8[j] = f2bf(((const float*)&f[j])[e]);
            *(bf16x8*)(xs + xsw(p, chg * 8)) = pk.v;
        }
    }
    // ---- stage edge cols sc=0 / sc=49 ----
    if (tid < 96) {
        int chg  = tid / 12;
        int rest = tid - chg * 12;
        int row  = rest >> 1;
        int sc   = (rest & 1) ? 49 : 0;
        int gr = r0 + row - 1, gc = c0 + sc - 1;
        bool in = (gr >= 0 && gr < H_ && gc >= 0 && gc < W_);
        union { bf16x8 v; unsigned short s8[8]; } pk;
#pragma unroll
        for (int j = 0; j < 8; ++j) {
            float vv = 0.f;
            if (in) vv = x[((size_t)(b * 64 + chg * 8 + j) * H_ + gr) * W_ + gc];
            pk.s8[j] = f2bf(vv);
        }
        *(bf16x8*)(xs + xsw(row * 50 + sc, chg * 8)) = pk.v;
    }

    f32x4 acc[3][4];
#pragma unroll
    for (int i = 0; i < 3; ++i)
#pragma unroll
        for (int j = 0; j < 4; ++j) acc[i][j] = (f32x4){0.f, 0.f, 0.f, 0.f};

    __syncthreads();   // the ONE barrier

    // ---- K loop: 9 taps; B ping-pong register prefetch (tap+1 in flight) ----
#pragma unroll
    for (int tap = 0; tap < 9; ++tap) {
        if (tap < 8) {
#pragma unroll
            for (int nt = 0; nt < 4; ++nt)
#pragma unroll
                for (int ks = 0; ks < 2; ++ks)
                    bnxt[nt][ks] = *(const bf16x8*)(wbase + (tap + 1) * 4096 + nt * 1024 + ks * 32);
        }
        const int dr = tap / 3, dc = tap % 3;
#pragma unroll
        for (int cb = 0; cb < 3; ++cb) {
            const int p = (wv + dr) * 50 + cb * 16 + n0 + dc;
            bf16x8 a0 = *(const bf16x8*)(xs + p * 64 + ((q ^ (p & 7)) << 3));
            bf16x8 a1 = *(const bf16x8*)(xs + p * 64 + (((q + 4) ^ (p & 7)) << 3));
#pragma unroll
            for (int nt = 0; nt < 4; ++nt) {
                acc[cb][nt] = __builtin_amdgcn_mfma_f32_16x16x32_bf16(a0, bcur[nt][0], acc[cb][nt], 0, 0, 0);
                acc[cb][nt] = __builtin_amdgcn_mfma_f32_16x16x32_bf16(a1, bcur[nt][1], acc[cb][nt], 0, 0, 0);
            }
        }
        if (tap < 8) {
#pragma unroll
            for (int nt = 0; nt < 4; ++nt)
#pragma unroll
                for (int ks = 0; ks < 2; ++ks)
                    bcur[nt][ks] = bnxt[nt][ks];
        }
    }

    // ---- epilogue: depthwise from xs + kern/bias (L2-hot) ----
    const float* kp = kern + b * 576;
#pragma unroll
    for (int nt = 0; nt < 4; ++nt) {
        const int n = nt * 16 + n0;
        float kw[9];
#pragma unroll
        for (int j = 0; j < 9; ++j) kw[j] = kp[n * 9 + j];
        const float bias = conv_b[n];
        const int gn = n >> 3, n7 = n & 7;
#pragma unroll
        for (int cb = 0; cb < 3; ++cb) {
            const int colb = cb * 16 + q * 4;
            float xw[3][6];
#pragma unroll
            for (int d = 0; d < 3; ++d)
#pragma unroll
                for (int cc = 0; cc < 6; ++cc) {
                    int p = (wv + d) * 50 + colb + cc;
                    xw[d][cc] = bf2f(xs[p * 64 + ((gn ^ (p & 7)) << 3) + n7]);
                }
            float4 st;
#pragma unroll
            for (int r = 0; r < 4; ++r) {
                float dw = 0.f;
#pragma unroll
                for (int d = 0; d < 3; ++d)
#pragma unroll
                    for (int e = 0; e < 3; ++e)
                        dw += kw[d * 3 + e] * xw[d][r + e];
                float v = (dw > 0.f ? dw : 0.1f * dw) + acc[cb][nt][r] + bias;
                ((float*)&st)[r] = v;
            }
            *(float4*)(out + ((size_t)(b * 64 + n) * H_ + (r0 + wv)) * W_ + c0 + colb) = st;
        }
    }
}

extern "C" void kernel_launch(void* const* d_in, const int* in_sizes, int n_in,
                              void* d_out, int out_size, void* d_ws, size_t ws_size,
                              hipStream_t stream) {
    const float* x      = (const float*)d_in[0];
    const float* k_v    = (const float*)d_in[1];
    const float* W1     = (const float*)d_in[2];
    const float* W2     = (const float*)d_in[3];
    const float* conv_w = (const float*)d_in[4];
    const float* conv_b = (const float*)d_in[5];
    float* outp = (float*)d_out;

    float* kern        = (float*)d_ws;                               // 36864 B
    unsigned short* wT = (unsigned short*)((char*)d_ws + 40960);     // 73728 B

    prep<<<160, 256, 0, stream>>>(k_v, W1, W2, conv_w, kern, wT);
    dim3 grid(4, 48, 16);
    fused_conv<<<grid, 256, 0, stream>>>(x, wT, kern, conv_b, outp);
}